// Round 6
// baseline (258.330 us; speedup 1.0000x reference)
//
#include <hip/hip_runtime.h>
#include <math.h>

// ---------------------------------------------------------------------------
// GaitGraph: standardize -> GCN(2->64)+ReLU -> GCN(64->64)+ReLU -> mean-pool
//            -> linear 64->3.   N=50000, E=800000, G=2048, H=64.
// R1: dst-CSR + pull-gather (585 -> 327us).
// R4: rank-2 layer-1 collapse + register-tile GEMM + sorted pooling (-> 237us).
// R6: (a) swap GEMM/aggregation in layer 2: aggregate y1 (recomputed on the
//         fly from 2-scalar S, 400KB L2-resident table) instead of gathering
//         h2 rows (12.8MB table, 83MB fetch). GEMM @W2 moves post-agg.
//     (b) fold finalize->agg2, dinv->scan1, detect->stats, gsearch->poolcls
//         (16 -> 12 dispatches).
// ---------------------------------------------------------------------------

#define H 64

__device__ __forceinline__ float nan0(float v) {
    return isfinite(v) ? v : 0.0f;
}

// Load index i from a buffer that is either int32 or int64 (flag is64).
__device__ __forceinline__ int ld_idx(const void* p, long long i, int is64) {
    if (is64) return (int)((const long long*)p)[i];
    return ((const int*)p)[i];
}

// Column sums + sumsq of the 2 input features (with nan_to_num).
// Block 0 additionally detects int64 vs int32 for edge_index and batch
// (odd int32 words all zero => int64 high words).
__global__ void k_stats(const float* __restrict__ x, int N,
                        float* __restrict__ stats,
                        const int* ei, int nEi, const int* batch, int nB,
                        int* flags) {
    if (blockIdx.x == 0) {
        __shared__ int nz_e, nz_b;
        if (threadIdx.x == 0) { nz_e = 0; nz_b = 0; }
        __syncthreads();
        int i = threadIdx.x;  // 0..255
        long long pe = 1 + 2 * ((long long)i * ((nEi - 2) / 2) / 256);
        if (pe < nEi && ei[pe] != 0) nz_e = 1;
        long long pb = 1 + 2 * ((long long)i * ((nB - 2) / 2) / 256);
        if (pb < nB && batch[pb] != 0) nz_b = 1;
        __syncthreads();
        if (threadIdx.x == 0) {
            flags[0] = (nz_e == 0);
            flags[1] = (nz_b == 0);
        }
    }
    float s0 = 0, s1 = 0, q0 = 0, q1 = 0;
    int tid = blockIdx.x * blockDim.x + threadIdx.x;
    int stride = gridDim.x * blockDim.x;
    for (int n = tid; n < N; n += stride) {
        float2 v = reinterpret_cast<const float2*>(x)[n];
        float a = nan0(v.x), b = nan0(v.y);
        s0 += a; s1 += b; q0 += a * a; q1 += b * b;
    }
    for (int m = 32; m >= 1; m >>= 1) {
        s0 += __shfl_down(s0, m);
        s1 += __shfl_down(s1, m);
        q0 += __shfl_down(q0, m);
        q1 += __shfl_down(q1, m);
    }
    __shared__ float red[4][4];
    int w = threadIdx.x >> 6, lane = threadIdx.x & 63;
    if (lane == 0) { red[w][0] = s0; red[w][1] = s1; red[w][2] = q0; red[w][3] = q1; }
    __syncthreads();
    if (threadIdx.x == 0) {
        int nw = blockDim.x >> 6;
        float t0 = 0, t1 = 0, t2 = 0, t3 = 0;
        for (int i = 0; i < nw; i++) {
            t0 += red[i][0]; t1 += red[i][1]; t2 += red[i][2]; t3 += red[i][3];
        }
        atomicAdd(&stats[0], t0);
        atomicAdd(&stats[1], t1);
        atomicAdd(&stats[2], t2);
        atomicAdd(&stats[3], t3);
    }
}

// In-degree histogram over dst (self-loops handled as +1 later).
__global__ void k_deg(const void* ei, int E, int* __restrict__ counts,
                      const int* __restrict__ flags) {
    int e = blockIdx.x * blockDim.x + threadIdx.x;
    if (e >= E) return;
    int is64 = flags[0];
    int d = ld_idx(ei, (long long)E + e, is64);
    atomicAdd(&counts[d], 1);
}

// Block-level exclusive scan of counts + dinv computation (fused).
__global__ void k_scan1(const int* __restrict__ counts, int* __restrict__ part,
                        int* __restrict__ bsum, float* __restrict__ dinv,
                        int N) {
    __shared__ int tmp[256];
    int i = blockIdx.x * 256 + threadIdx.x;
    int v = (i < N) ? counts[i] : 0;
    tmp[threadIdx.x] = v;
    __syncthreads();
    for (int off = 1; off < 256; off <<= 1) {
        int t = (threadIdx.x >= off) ? tmp[threadIdx.x - off] : 0;
        __syncthreads();
        tmp[threadIdx.x] += t;
        __syncthreads();
    }
    if (i < N) {
        part[i] = tmp[threadIdx.x] - v;  // exclusive within block
        dinv[i] = rsqrtf((float)(v + 1));
    }
    if (threadIdx.x == 255) bsum[blockIdx.x] = tmp[255];
}

__global__ void k_scan2(int* __restrict__ bsum, int nb) {  // nb <= 256
    __shared__ int tmp[256];
    int v = (threadIdx.x < nb) ? bsum[threadIdx.x] : 0;
    tmp[threadIdx.x] = v;
    __syncthreads();
    for (int off = 1; off < 256; off <<= 1) {
        int t = (threadIdx.x >= off) ? tmp[threadIdx.x - off] : 0;
        __syncthreads();
        tmp[threadIdx.x] += t;
        __syncthreads();
    }
    if (threadIdx.x < nb) bsum[threadIdx.x] = tmp[threadIdx.x] - v;
}

__global__ void k_scan3(const int* __restrict__ part, const int* __restrict__ bsum,
                        int* __restrict__ offsets, int* __restrict__ cursor,
                        int N, int E) {
    int i = blockIdx.x * 256 + threadIdx.x;
    if (i < N) {
        int o = part[i] + bsum[blockIdx.x];
        offsets[i] = o;
        cursor[i] = o;
    }
    if (i == 0) offsets[N] = E;
}

// Scatter edges into CSR buckets: entry = (src, dinv[src]*dinv[dst]).
__global__ void k_scatter(const void* ei, const float* __restrict__ dinv,
                          int* __restrict__ cursor, int2* __restrict__ csr,
                          int E, const int* __restrict__ flags) {
    int e = blockIdx.x * blockDim.x + threadIdx.x;
    if (e >= E) return;
    int is64 = flags[0];
    int s = ld_idx(ei, e, is64);
    int d = ld_idx(ei, (long long)E + e, is64);
    float w = dinv[s] * dinv[d];
    int pos = atomicAdd(&cursor[d], 1);
    csr[pos] = make_int2(s, __float_as_int(w));
}

// Layer-1 rank-2 aggregation: S[d] = Sigma_e w*(std feats of src) + dinv^2*(std
// feats of d). Standardization params computed inline from raw sums.
__global__ void k_agg2(const int2* __restrict__ csr,
                       const int* __restrict__ offsets,
                       const float* __restrict__ x,
                       const float* __restrict__ stats,
                       const float* __restrict__ dinv,
                       float2* __restrict__ S, int N) {
    int n = blockIdx.x * blockDim.x + threadIdx.x;
    if (n >= N) return;
    float sum0 = stats[0], sum1 = stats[1], q0 = stats[2], q1 = stats[3];
    float mu0 = sum0 / N, mu1 = sum1 / N;
    float v0 = fmaxf((q0 - sum0 * sum0 / N) / (N - 1), 0.0f);
    float v1 = fmaxf((q1 - sum1 * sum1 / N) / (N - 1), 0.0f);
    float r0 = 1.0f / (sqrtf(v0) + 1e-6f);
    float r1 = 1.0f / (sqrtf(v1) + 1e-6f);
    float2 xn = reinterpret_cast<const float2*>(x)[n];
    float di = dinv[n];
    float s0 = di * di * (nan0(xn.x) - mu0) * r0;
    float s1 = di * di * (nan0(xn.y) - mu1) * r1;
    int beg = offsets[n], end = offsets[n + 1];
    for (int k = beg; k < end; k++) {
        int2 e = csr[k];
        float w = __int_as_float(e.y);
        float2 xs = reinterpret_cast<const float2*>(x)[e.x];
        s0 += w * (nan0(xs.x) - mu0) * r0;
        s1 += w * (nan0(xs.y) - mu1) * r1;
    }
    S[n] = make_float2(s0, s1);
}

// Layer-2 aggregation over y1, with y1 recomputed on the fly from S:
// aggY[d][j] = Sigma_e w * relu(S0[s]*W1[0][j]+S1[s]*W1[1][j]+b1[j])
//            + dinv^2 * relu(... S[d] ...).
// Wave per dst node; lane j = feature. S table = 400KB (L2-resident gather).
__global__ __launch_bounds__(256) void k_gath2(
    const int2* __restrict__ csr, const int* __restrict__ offsets,
    const float2* __restrict__ S, const float* __restrict__ dinv,
    const float* __restrict__ W1, const float* __restrict__ b1,
    float* __restrict__ aggY, int N) {
    int t = blockIdx.x * blockDim.x + threadIdx.x;
    int n = t >> 6, j = t & 63;
    if (n >= N) return;
    float w10 = W1[j], w11 = W1[H + j], bb = b1[j];
    float di = dinv[n];
    float2 sn = S[n];
    float acc = fmaxf(sn.x * w10 + sn.y * w11 + bb, 0.0f) * (di * di);
    int beg = offsets[n], end = offsets[n + 1];
    for (int base = beg; base < end; base += 64) {
        int cnt = min(64, end - base);
        int2 entry; float2 sv;
        if (base + j < end) { entry = csr[base + j]; sv = S[entry.x]; }
        for (int k = 0; k < cnt; k++) {
            float s0 = __shfl(sv.x, k);
            float s1 = __shfl(sv.y, k);
            float w = __int_as_float(__shfl(entry.y, k));
            acc += fmaxf(s0 * w10 + s1 * w11 + bb, 0.0f) * w;
        }
    }
    aggY[(size_t)n * H + j] = acc;
}

// Bout = relu(aggY @ W2 + b2). 64x64 block tile, 4x4 register tile/thread.
// At padded to 68 cols: transposed store is 8-way (rare), float4 reads free.
__global__ __launch_bounds__(256) void k_gemmB(
    const float* __restrict__ A, const float* __restrict__ W2,
    const float* __restrict__ b2, float* __restrict__ Bout, int N) {
    __shared__ float At[64][68];  // At[k][r] = A[r][k]
    __shared__ float Ws[64][64];  // Ws[k][c]
    __shared__ float bs[64];
    int tid = threadIdx.x;
    int rbase = blockIdx.x * 64;
    for (int i = tid; i < 64 * 64; i += 256) Ws[i >> 6][i & 63] = W2[i];
    if (tid < 64) bs[tid] = b2[tid];
    int rows = min(64, N - rbase);
    for (int i = tid; i < 64 * 64; i += 256) {
        int r = i >> 6, k = i & 63;
        int rr = min(r, rows - 1);  // clamp; extra rows masked on store
        At[k][r] = A[(size_t)(rbase + rr) * H + k];
    }
    __syncthreads();
    int rg = (tid & 15) * 4;  // row group
    int cg = (tid >> 4) * 4;  // col group
    float acc[4][4] = {{0}};
#pragma unroll
    for (int k = 0; k < 64; k++) {
        float4 a = *reinterpret_cast<const float4*>(&At[k][rg]);
        float4 b = *reinterpret_cast<const float4*>(&Ws[k][cg]);
        acc[0][0] += a.x * b.x; acc[0][1] += a.x * b.y;
        acc[0][2] += a.x * b.z; acc[0][3] += a.x * b.w;
        acc[1][0] += a.y * b.x; acc[1][1] += a.y * b.y;
        acc[1][2] += a.y * b.z; acc[1][3] += a.y * b.w;
        acc[2][0] += a.z * b.x; acc[2][1] += a.z * b.y;
        acc[2][2] += a.z * b.z; acc[2][3] += a.z * b.w;
        acc[3][0] += a.w * b.x; acc[3][1] += a.w * b.y;
        acc[3][2] += a.w * b.z; acc[3][3] += a.w * b.w;
    }
#pragma unroll
    for (int i2 = 0; i2 < 4; i2++) {
        int r = rbase + rg + i2;
        if (r < N) {
            *reinterpret_cast<float4*>(&Bout[(size_t)r * H + cg]) = make_float4(
                fmaxf(acc[i2][0] + bs[cg + 0], 0.0f),
                fmaxf(acc[i2][1] + bs[cg + 1], 0.0f),
                fmaxf(acc[i2][2] + bs[cg + 2], 0.0f),
                fmaxf(acc[i2][3] + bs[cg + 3], 0.0f));
        }
    }
}

// Mean-pool per graph (sorted batch; inline binary search) + 64x3 classify.
// Wave per graph; lane j = feature. Searches are wave-uniform.
__global__ __launch_bounds__(256) void k_poolcls(
    const float* __restrict__ B, const void* batch,
    const float* __restrict__ Wc, const float* __restrict__ bc,
    float* __restrict__ out, int N, int G, const int* __restrict__ flags) {
    int t = blockIdx.x * blockDim.x + threadIdx.x;
    int g = t >> 6, j = t & 63;
    if (g >= G) return;
    int is64 = flags[1];
    int beg, end;
    {
        int lo = 0, hi = N;
        while (lo < hi) {
            int mid = (lo + hi) >> 1;
            if (ld_idx(batch, mid, is64) < g) lo = mid + 1; else hi = mid;
        }
        beg = lo;
    }
    {
        int lo = beg, hi = N;
        while (lo < hi) {
            int mid = (lo + hi) >> 1;
            if (ld_idx(batch, mid, is64) < g + 1) lo = mid + 1; else hi = mid;
        }
        end = lo;
    }
    float acc = 0.0f;
    for (int n = beg; n < end; n++) acc += B[(size_t)n * H + j];
    float p = acc / (float)max(end - beg, 1);
#pragma unroll
    for (int c = 0; c < 3; c++) {
        float v = p * Wc[j * 3 + c];
        for (int m = 32; m >= 1; m >>= 1) v += __shfl_xor(v, m);
        if (j == 0) out[g * 3 + c] = v + bc[c];
    }
}

extern "C" void kernel_launch(void* const* d_in, const int* in_sizes, int n_in,
                              void* d_out, int out_size, void* d_ws,
                              size_t ws_size, hipStream_t stream) {
    const float* x  = (const float*)d_in[0];
    const float* W1 = (const float*)d_in[1];
    const float* b1 = (const float*)d_in[2];
    const float* W2 = (const float*)d_in[3];
    const float* b2 = (const float*)d_in[4];
    const float* Wc = (const float*)d_in[5];
    const float* bc = (const float*)d_in[6];
    const void*  ei = d_in[7];
    const void*  batch = d_in[8];

    int N = in_sizes[0] / 2;
    int E = in_sizes[7] / 2;
    int G = out_size / 3;

    // Workspace layout (8B-aligned entries first).
    int2*   csr     = (int2*)d_ws;                 // [E]
    float2* S       = (float2*)(csr + E);          // [N]
    float*  A       = (float*)(S + N);             // [N,64] aggY
    float*  B       = A + (size_t)N * H;           // [N,64] layer-2 out
    float*  dinv    = B + (size_t)N * H;           // [N]
    float*  stats   = dinv + N;                    // [8]
    int*    flags   = (int*)(stats + 8);           // [2]
    int*    counts  = flags + 2;                   // [N]
    int*    part    = counts + N;                  // [N]
    int*    bsum    = part + N;                    // [256]
    int*    offsets = bsum + 256;                  // [N+1]
    int*    cursor  = offsets + N + 1;             // [N]

    float* out = (float*)d_out;

    int nblk_n256 = (N + 255) / 256;
    int nblk_e = (E + 255) / 256;

    hipMemsetAsync(stats, 0, 8 * sizeof(float), stream);
    hipMemsetAsync(counts, 0, (size_t)N * sizeof(int), stream);

    k_stats<<<128, 256, 0, stream>>>(x, N, stats, (const int*)ei, in_sizes[7],
                                     (const int*)batch, in_sizes[8], flags);

    // CSR build
    k_deg<<<nblk_e, 256, 0, stream>>>(ei, E, counts, flags);
    k_scan1<<<nblk_n256, 256, 0, stream>>>(counts, part, bsum, dinv, N);
    k_scan2<<<1, 256, 0, stream>>>(bsum, nblk_n256);
    k_scan3<<<nblk_n256, 256, 0, stream>>>(part, bsum, offsets, cursor, N, E);
    k_scatter<<<nblk_e, 256, 0, stream>>>(ei, dinv, cursor, csr, E, flags);

    // Layer 1 (rank-2 collapsed aggregation)
    k_agg2<<<nblk_n256, 256, 0, stream>>>(csr, offsets, x, stats, dinv, S, N);

    // Layer 2: aggregate y1 (recomputed from S on the fly), then GEMM @W2.
    k_gath2<<<(N + 3) / 4, 256, 0, stream>>>(csr, offsets, S, dinv, W1, b1, A, N);
    k_gemmB<<<(N + 63) / 64, 256, 0, stream>>>(A, W2, b2, B, N);

    // Pool + classify (sorted batch, inline search)
    k_poolcls<<<(G * H + 255) / 256, 256, 0, stream>>>(B, batch, Wc, bc, out,
                                                       N, G, flags);
}

// Round 7
// 186.637 us; speedup vs baseline: 1.3841x; 1.3841x over previous
//
#include <hip/hip_runtime.h>
#include <math.h>

// ---------------------------------------------------------------------------
// GaitGraph: standardize -> GCN(2->64)+ReLU -> GCN(64->64)+ReLU -> mean-pool
//            -> linear 64->3.   N=50000, E=800000, G=2048, H=64.
// R1: dst-CSR + pull-gather (585 -> 327us).
// R4: rank-2 layer-1 collapse + register-tile GEMM + sorted pooling (-> 237us).
// R6: layer-2 GEMM/aggregation swap (gather 2-scalar S, L2-resident).
// R7: fix k_gemmB pathology (VGPR=256 spill -> 74MB scratch writes, 1.9M LDS
//     bank conflicts): launch_bounds(256,4) + unroll 8 caps registers;
//     staging re-mapped so LDS writes hit consecutive banks (row-per-lane).
// ---------------------------------------------------------------------------

#define H 64

__device__ __forceinline__ float nan0(float v) {
    return isfinite(v) ? v : 0.0f;
}

// Load index i from a buffer that is either int32 or int64 (flag is64).
__device__ __forceinline__ int ld_idx(const void* p, long long i, int is64) {
    if (is64) return (int)((const long long*)p)[i];
    return ((const int*)p)[i];
}

// Column sums + sumsq of the 2 input features (with nan_to_num).
// Block 0 additionally detects int64 vs int32 for edge_index and batch
// (odd int32 words all zero => int64 high words).
__global__ void k_stats(const float* __restrict__ x, int N,
                        float* __restrict__ stats,
                        const int* ei, int nEi, const int* batch, int nB,
                        int* flags) {
    if (blockIdx.x == 0) {
        __shared__ int nz_e, nz_b;
        if (threadIdx.x == 0) { nz_e = 0; nz_b = 0; }
        __syncthreads();
        int i = threadIdx.x;  // 0..255
        long long pe = 1 + 2 * ((long long)i * ((nEi - 2) / 2) / 256);
        if (pe < nEi && ei[pe] != 0) nz_e = 1;
        long long pb = 1 + 2 * ((long long)i * ((nB - 2) / 2) / 256);
        if (pb < nB && batch[pb] != 0) nz_b = 1;
        __syncthreads();
        if (threadIdx.x == 0) {
            flags[0] = (nz_e == 0);
            flags[1] = (nz_b == 0);
        }
    }
    float s0 = 0, s1 = 0, q0 = 0, q1 = 0;
    int tid = blockIdx.x * blockDim.x + threadIdx.x;
    int stride = gridDim.x * blockDim.x;
    for (int n = tid; n < N; n += stride) {
        float2 v = reinterpret_cast<const float2*>(x)[n];
        float a = nan0(v.x), b = nan0(v.y);
        s0 += a; s1 += b; q0 += a * a; q1 += b * b;
    }
    for (int m = 32; m >= 1; m >>= 1) {
        s0 += __shfl_down(s0, m);
        s1 += __shfl_down(s1, m);
        q0 += __shfl_down(q0, m);
        q1 += __shfl_down(q1, m);
    }
    __shared__ float red[4][4];
    int w = threadIdx.x >> 6, lane = threadIdx.x & 63;
    if (lane == 0) { red[w][0] = s0; red[w][1] = s1; red[w][2] = q0; red[w][3] = q1; }
    __syncthreads();
    if (threadIdx.x == 0) {
        int nw = blockDim.x >> 6;
        float t0 = 0, t1 = 0, t2 = 0, t3 = 0;
        for (int i = 0; i < nw; i++) {
            t0 += red[i][0]; t1 += red[i][1]; t2 += red[i][2]; t3 += red[i][3];
        }
        atomicAdd(&stats[0], t0);
        atomicAdd(&stats[1], t1);
        atomicAdd(&stats[2], t2);
        atomicAdd(&stats[3], t3);
    }
}

// In-degree histogram over dst (self-loops handled as +1 later).
__global__ void k_deg(const void* ei, int E, int* __restrict__ counts,
                      const int* __restrict__ flags) {
    int e = blockIdx.x * blockDim.x + threadIdx.x;
    if (e >= E) return;
    int is64 = flags[0];
    int d = ld_idx(ei, (long long)E + e, is64);
    atomicAdd(&counts[d], 1);
}

// Block-level exclusive scan of counts + dinv computation (fused).
__global__ void k_scan1(const int* __restrict__ counts, int* __restrict__ part,
                        int* __restrict__ bsum, float* __restrict__ dinv,
                        int N) {
    __shared__ int tmp[256];
    int i = blockIdx.x * 256 + threadIdx.x;
    int v = (i < N) ? counts[i] : 0;
    tmp[threadIdx.x] = v;
    __syncthreads();
    for (int off = 1; off < 256; off <<= 1) {
        int t = (threadIdx.x >= off) ? tmp[threadIdx.x - off] : 0;
        __syncthreads();
        tmp[threadIdx.x] += t;
        __syncthreads();
    }
    if (i < N) {
        part[i] = tmp[threadIdx.x] - v;  // exclusive within block
        dinv[i] = rsqrtf((float)(v + 1));
    }
    if (threadIdx.x == 255) bsum[blockIdx.x] = tmp[255];
}

__global__ void k_scan2(int* __restrict__ bsum, int nb) {  // nb <= 256
    __shared__ int tmp[256];
    int v = (threadIdx.x < nb) ? bsum[threadIdx.x] : 0;
    tmp[threadIdx.x] = v;
    __syncthreads();
    for (int off = 1; off < 256; off <<= 1) {
        int t = (threadIdx.x >= off) ? tmp[threadIdx.x - off] : 0;
        __syncthreads();
        tmp[threadIdx.x] += t;
        __syncthreads();
    }
    if (threadIdx.x < nb) bsum[threadIdx.x] = tmp[threadIdx.x] - v;
}

__global__ void k_scan3(const int* __restrict__ part, const int* __restrict__ bsum,
                        int* __restrict__ offsets, int* __restrict__ cursor,
                        int N, int E) {
    int i = blockIdx.x * 256 + threadIdx.x;
    if (i < N) {
        int o = part[i] + bsum[blockIdx.x];
        offsets[i] = o;
        cursor[i] = o;
    }
    if (i == 0) offsets[N] = E;
}

// Scatter edges into CSR buckets: entry = (src, dinv[src]*dinv[dst]).
__global__ void k_scatter(const void* ei, const float* __restrict__ dinv,
                          int* __restrict__ cursor, int2* __restrict__ csr,
                          int E, const int* __restrict__ flags) {
    int e = blockIdx.x * blockDim.x + threadIdx.x;
    if (e >= E) return;
    int is64 = flags[0];
    int s = ld_idx(ei, e, is64);
    int d = ld_idx(ei, (long long)E + e, is64);
    float w = dinv[s] * dinv[d];
    int pos = atomicAdd(&cursor[d], 1);
    csr[pos] = make_int2(s, __float_as_int(w));
}

// Layer-1 rank-2 aggregation: S[d] = Sigma_e w*(std feats of src) + dinv^2*(std
// feats of d). Standardization params computed inline from raw sums.
__global__ void k_agg2(const int2* __restrict__ csr,
                       const int* __restrict__ offsets,
                       const float* __restrict__ x,
                       const float* __restrict__ stats,
                       const float* __restrict__ dinv,
                       float2* __restrict__ S, int N) {
    int n = blockIdx.x * blockDim.x + threadIdx.x;
    if (n >= N) return;
    float sum0 = stats[0], sum1 = stats[1], q0 = stats[2], q1 = stats[3];
    float mu0 = sum0 / N, mu1 = sum1 / N;
    float v0 = fmaxf((q0 - sum0 * sum0 / N) / (N - 1), 0.0f);
    float v1 = fmaxf((q1 - sum1 * sum1 / N) / (N - 1), 0.0f);
    float r0 = 1.0f / (sqrtf(v0) + 1e-6f);
    float r1 = 1.0f / (sqrtf(v1) + 1e-6f);
    float2 xn = reinterpret_cast<const float2*>(x)[n];
    float di = dinv[n];
    float s0 = di * di * (nan0(xn.x) - mu0) * r0;
    float s1 = di * di * (nan0(xn.y) - mu1) * r1;
    int beg = offsets[n], end = offsets[n + 1];
    for (int k = beg; k < end; k++) {
        int2 e = csr[k];
        float w = __int_as_float(e.y);
        float2 xs = reinterpret_cast<const float2*>(x)[e.x];
        s0 += w * (nan0(xs.x) - mu0) * r0;
        s1 += w * (nan0(xs.y) - mu1) * r1;
    }
    S[n] = make_float2(s0, s1);
}

// Layer-2 aggregation over y1, with y1 recomputed on the fly from S:
// aggY[d][j] = Sigma_e w * relu(S0[s]*W1[0][j]+S1[s]*W1[1][j]+b1[j])
//            + dinv^2 * relu(... S[d] ...).
// Wave per dst node; lane j = feature. S table = 400KB (L2-resident gather).
__global__ __launch_bounds__(256) void k_gath2(
    const int2* __restrict__ csr, const int* __restrict__ offsets,
    const float2* __restrict__ S, const float* __restrict__ dinv,
    const float* __restrict__ W1, const float* __restrict__ b1,
    float* __restrict__ aggY, int N) {
    int t = blockIdx.x * blockDim.x + threadIdx.x;
    int n = t >> 6, j = t & 63;
    if (n >= N) return;
    float w10 = W1[j], w11 = W1[H + j], bb = b1[j];
    float di = dinv[n];
    float2 sn = S[n];
    float acc = fmaxf(sn.x * w10 + sn.y * w11 + bb, 0.0f) * (di * di);
    int beg = offsets[n], end = offsets[n + 1];
    for (int base = beg; base < end; base += 64) {
        int cnt = min(64, end - base);
        int2 entry; float2 sv;
        if (base + j < end) { entry = csr[base + j]; sv = S[entry.x]; }
        for (int k = 0; k < cnt; k++) {
            float s0 = __shfl(sv.x, k);
            float s1 = __shfl(sv.y, k);
            float w = __int_as_float(__shfl(entry.y, k));
            acc += fmaxf(s0 * w10 + s1 * w11 + bb, 0.0f) * w;
        }
    }
    aggY[(size_t)n * H + j] = acc;
}

// Bout = relu(aggY @ W2 + b2). 64x64 block tile, 4x4 register tile/thread.
// R7: launch_bounds(256,4) caps VGPR at 128 (R6 hit 256 + scratch spill);
//     unroll 8 keeps live ranges short; staging writes At[k][row] with
//     row-per-lane (consecutive banks, conflict-free); reads are float4 at
//     pitch 68 (2-way aliasing = free).
__global__ __launch_bounds__(256, 4) void k_gemmB(
    const float* __restrict__ A, const float* __restrict__ W2,
    const float* __restrict__ b2, float* __restrict__ Bout, int N) {
    __shared__ float At[64][68];  // At[k][r] = A[r][k], padded pitch 68
    __shared__ float Ws[64][64];  // Ws[k][c]
    __shared__ float bs[64];
    int tid = threadIdx.x;
    int rbase = blockIdx.x * 64;
    for (int i = tid; i < 64 * 64; i += 256) Ws[i >> 6][i & 63] = W2[i];
    if (tid < 64) bs[tid] = b2[tid];
    // Staging: lane owns one row; wave w covers k-quads w, w+4, w+8, w+12.
    {
        int row = tid & 63;
        int r_glob = min(rbase + row, N - 1);  // clamp; extras masked on store
        const float4* Arow =
            reinterpret_cast<const float4*>(&A[(size_t)r_glob * H]);
        for (int kq = (tid >> 6); kq < 16; kq += 4) {
            float4 v = Arow[kq];
            At[kq * 4 + 0][row] = v.x;
            At[kq * 4 + 1][row] = v.y;
            At[kq * 4 + 2][row] = v.z;
            At[kq * 4 + 3][row] = v.w;
        }
    }
    __syncthreads();
    int rg = (tid & 15) * 4;  // row group
    int cg = (tid >> 4) * 4;  // col group
    float acc[4][4] = {{0}};
#pragma unroll 8
    for (int k = 0; k < 64; k++) {
        float4 a = *reinterpret_cast<const float4*>(&At[k][rg]);
        float4 b = *reinterpret_cast<const float4*>(&Ws[k][cg]);
        acc[0][0] += a.x * b.x; acc[0][1] += a.x * b.y;
        acc[0][2] += a.x * b.z; acc[0][3] += a.x * b.w;
        acc[1][0] += a.y * b.x; acc[1][1] += a.y * b.y;
        acc[1][2] += a.y * b.z; acc[1][3] += a.y * b.w;
        acc[2][0] += a.z * b.x; acc[2][1] += a.z * b.y;
        acc[2][2] += a.z * b.z; acc[2][3] += a.z * b.w;
        acc[3][0] += a.w * b.x; acc[3][1] += a.w * b.y;
        acc[3][2] += a.w * b.z; acc[3][3] += a.w * b.w;
    }
#pragma unroll
    for (int i2 = 0; i2 < 4; i2++) {
        int r = rbase + rg + i2;
        if (r < N) {
            *reinterpret_cast<float4*>(&Bout[(size_t)r * H + cg]) = make_float4(
                fmaxf(acc[i2][0] + bs[cg + 0], 0.0f),
                fmaxf(acc[i2][1] + bs[cg + 1], 0.0f),
                fmaxf(acc[i2][2] + bs[cg + 2], 0.0f),
                fmaxf(acc[i2][3] + bs[cg + 3], 0.0f));
        }
    }
}

// Mean-pool per graph (sorted batch; inline binary search) + 64x3 classify.
// Wave per graph; lane j = feature. Searches are wave-uniform.
__global__ __launch_bounds__(256) void k_poolcls(
    const float* __restrict__ B, const void* batch,
    const float* __restrict__ Wc, const float* __restrict__ bc,
    float* __restrict__ out, int N, int G, const int* __restrict__ flags) {
    int t = blockIdx.x * blockDim.x + threadIdx.x;
    int g = t >> 6, j = t & 63;
    if (g >= G) return;
    int is64 = flags[1];
    int beg, end;
    {
        int lo = 0, hi = N;
        while (lo < hi) {
            int mid = (lo + hi) >> 1;
            if (ld_idx(batch, mid, is64) < g) lo = mid + 1; else hi = mid;
        }
        beg = lo;
    }
    {
        int lo = beg, hi = N;
        while (lo < hi) {
            int mid = (lo + hi) >> 1;
            if (ld_idx(batch, mid, is64) < g + 1) lo = mid + 1; else hi = mid;
        }
        end = lo;
    }
    float acc = 0.0f;
    for (int n = beg; n < end; n++) acc += B[(size_t)n * H + j];
    float p = acc / (float)max(end - beg, 1);
#pragma unroll
    for (int c = 0; c < 3; c++) {
        float v = p * Wc[j * 3 + c];
        for (int m = 32; m >= 1; m >>= 1) v += __shfl_xor(v, m);
        if (j == 0) out[g * 3 + c] = v + bc[c];
    }
}

extern "C" void kernel_launch(void* const* d_in, const int* in_sizes, int n_in,
                              void* d_out, int out_size, void* d_ws,
                              size_t ws_size, hipStream_t stream) {
    const float* x  = (const float*)d_in[0];
    const float* W1 = (const float*)d_in[1];
    const float* b1 = (const float*)d_in[2];
    const float* W2 = (const float*)d_in[3];
    const float* b2 = (const float*)d_in[4];
    const float* Wc = (const float*)d_in[5];
    const float* bc = (const float*)d_in[6];
    const void*  ei = d_in[7];
    const void*  batch = d_in[8];

    int N = in_sizes[0] / 2;
    int E = in_sizes[7] / 2;
    int G = out_size / 3;

    // Workspace layout (8B-aligned entries first).
    int2*   csr     = (int2*)d_ws;                 // [E]
    float2* S       = (float2*)(csr + E);          // [N]
    float*  A       = (float*)(S + N);             // [N,64] aggY
    float*  B       = A + (size_t)N * H;           // [N,64] layer-2 out
    float*  dinv    = B + (size_t)N * H;           // [N]
    float*  stats   = dinv + N;                    // [8]
    int*    flags   = (int*)(stats + 8);           // [2]
    int*    counts  = flags + 2;                   // [N]
    int*    part    = counts + N;                  // [N]
    int*    bsum    = part + N;                    // [256]
    int*    offsets = bsum + 256;                  // [N+1]
    int*    cursor  = offsets + N + 1;             // [N]

    float* out = (float*)d_out;

    int nblk_n256 = (N + 255) / 256;
    int nblk_e = (E + 255) / 256;

    hipMemsetAsync(stats, 0, 8 * sizeof(float), stream);
    hipMemsetAsync(counts, 0, (size_t)N * sizeof(int), stream);

    k_stats<<<128, 256, 0, stream>>>(x, N, stats, (const int*)ei, in_sizes[7],
                                     (const int*)batch, in_sizes[8], flags);

    // CSR build
    k_deg<<<nblk_e, 256, 0, stream>>>(ei, E, counts, flags);
    k_scan1<<<nblk_n256, 256, 0, stream>>>(counts, part, bsum, dinv, N);
    k_scan2<<<1, 256, 0, stream>>>(bsum, nblk_n256);
    k_scan3<<<nblk_n256, 256, 0, stream>>>(part, bsum, offsets, cursor, N, E);
    k_scatter<<<nblk_e, 256, 0, stream>>>(ei, dinv, cursor, csr, E, flags);

    // Layer 1 (rank-2 collapsed aggregation)
    k_agg2<<<nblk_n256, 256, 0, stream>>>(csr, offsets, x, stats, dinv, S, N);

    // Layer 2: aggregate y1 (recomputed from S on the fly), then GEMM @W2.
    k_gath2<<<(N + 3) / 4, 256, 0, stream>>>(csr, offsets, S, dinv, W1, b1, A, N);
    k_gemmB<<<(N + 63) / 64, 256, 0, stream>>>(A, W2, b2, B, N);

    // Pool + classify (sorted batch, inline search)
    k_poolcls<<<(G * H + 255) / 256, 256, 0, stream>>>(B, batch, Wc, bc, out,
                                                       N, G, flags);
}